// Round 5
// baseline (523.894 us; speedup 1.0000x reference)
//
#include <hip/hip_runtime.h>
#include <hip/hip_bf16.h>
#include <stdint.h>

// ---------------------------------------------------------------------------
// Round 8: barrier-free wave-chains. 1 wave = 1 WG = 32 rows, owns the whole
// 8-layer chain privately. Zero __syncthreads; all LDS deps wave-local.
//  - LDS/WG: X [32][136] (staging + A_v), Y [32][136] (A_g), Z [32][72]
//    (mid quarter), mask = 22144 B -> 7 WGs/CU, each phase-decorrelated.
//  - gate regs eliminated: gate-L3 + val-L3 fused per column-quarter in the
//    final (acc_g 32 + acc_v 32, fp32 sigmoid, no packing, no long liveness).
//  - __launch_bounds__(64,2): cap 256, peak live ~145 -> no spill (r7b: the
//    128 cap spilled 250 MB of scratch; r6: cap 85 spilled 94 MB).
//  - B-reuse=1 (2.4 GB L2 weight traffic, ~70us L2 floor - acceptable).
// Same fragment-ordered ws layout + prep kernel as r4-r7 (verified).
// ---------------------------------------------------------------------------

typedef __attribute__((ext_vector_type(8))) short short8_t;
typedef __attribute__((ext_vector_type(16))) float f32x16;

#define ROWS 32
#define NWG  4096            // 131072 / 32
#define NTHR 64

// LDS layout (bytes)
#define OFF_X 0              // [32][136] shorts = 8704 (stream staging, then A_v)
#define OFF_Y 8704           // [32][136] shorts = 8704 (A_g)
#define OFF_Z 17408          // [32][72]  shorts = 4608 (mid-layer quarter buf)
#define OFF_M 22016          // 32 floats = 128
#define LDS_TOTAL 22144

__device__ __forceinline__ short f2bf(float f) {
  union { float f; uint32_t u; } v; v.f = f;
  uint32_t r = (v.u + 0x7FFFu + ((v.u >> 16) & 1u)) >> 16;  // RNE
  return (short)r;
}

// ---- MFMA block: A from LDS (row = lane&31), B coalesced from fragment-
// ordered global. Weight elem off = ((cb*KT16 + ks)<<9) + lane*8 + j
//   -> logical n = cb*32 + (lane&31), k = ks*16 + (lane>>5)*8 + j.
// A: lane n32 -> act row n32, k = ks*16 + q32*8 + j (local; ks0 offsets only
// B, so partial-K passes read A with local k). Dual k-mapping matches B's,
// so any k-permutation cancels in the dot product.
template <int KT16, int KSTEPS, int CT>
__device__ __forceinline__ void gemmW(const short* actin, int Sin,
                                      const short* __restrict__ wsB, int ks0, int cb0,
                                      f32x16 (&acc)[CT], int lane) {
  const int n32 = lane & 31, q32 = lane >> 5;
#pragma unroll
  for (int ks = 0; ks < KSTEPS; ++ks) {
    const int kl = ks * 16 + q32 * 8;
    short8_t b[CT];
#pragma unroll
    for (int ct = 0; ct < CT; ++ct)
      b[ct] = *(const short8_t*)(wsB + (((cb0 + ct) * KT16 + ks0 + ks) << 9) + lane * 8);
    const short8_t a = *(const short8_t*)(actin + n32 * Sin + kl);
#pragma unroll
    for (int ct = 0; ct < CT; ++ct)
      acc[ct] = __builtin_amdgcn_mfma_f32_32x32x16_bf16(a, b[ct], acc[ct], 0, 0, 0);
  }
}

// C/D layout (verified m74/m101): col = lane&31, row = (reg&3)+8*(reg>>2)+4*(lane>>5)
template <int CT, int ACTF>
__device__ __forceinline__ void epiW(f32x16 (&acc)[CT], short* actout, int Sout,
                                     const float* __restrict__ bias, int c0,
                                     int n32, int q32) {
#pragma unroll
  for (int ct = 0; ct < CT; ++ct) {
    const int c = c0 + ct * 32 + n32;
    const float bv = bias[c0 + ct * 32 + n32];
#pragma unroll
    for (int reg = 0; reg < 16; ++reg) {
      const int r = (reg & 3) + 8 * (reg >> 2) + 4 * q32;
      float v = acc[ct][reg] + bv;
      if (ACTF == 1) v = fmaxf(v, 0.f);
      actout[r * Sout + c] = f2bf(v);
    }
  }
}

// ---- input staging: one chunk = 32 rows x 128 cols fp32 -> bf16 LDS -------
// lane: c4 = lane&31 (16B col group), rh = lane>>5; it: rows r = 2*it + rh.
// mmode: 0 none, 1 init maskacc, 2 accumulate (mask = row-sum of h0).
template <bool MASKA>
__device__ __forceinline__ void stage_chunk(const float* __restrict__ src, int row0,
                                            int colbase, short* X, float* maskacc,
                                            int mmode, int lane) {
  const int c4 = lane & 31, rh = lane >> 5;
  float4 v[16];
#pragma unroll
  for (int it = 0; it < 16; ++it)
    v[it] = *(const float4*)(src + (size_t)(row0 + 2 * it + rh) * 256 + colbase + c4 * 4);
#pragma unroll
  for (int it = 0; it < 16; ++it) {
    const int r = 2 * it + rh;
    short4 pk; pk.x = f2bf(v[it].x); pk.y = f2bf(v[it].y); pk.z = f2bf(v[it].z); pk.w = f2bf(v[it].w);
    *(short4*)(X + r * 136 + c4 * 4) = pk;
    if (MASKA && mmode) {
      float s = v[it].x + v[it].y + v[it].z + v[it].w;
      s += __shfl_down(s, 16, 32);
      s += __shfl_down(s, 8, 32);
      s += __shfl_down(s, 4, 32);
      s += __shfl_down(s, 2, 32);
      s += __shfl_down(s, 1, 32);
      if (c4 == 0) {
        if (mmode == 1) maskacc[r] = s; else maskacc[r] += s;
      }
    }
  }
}

// Streamed first layer (K = NCH*128, N=128 out, CT=4). Chunks kc<splitc from
// src0, else src1. Output -> Aout [32][136].
template <int NCH, bool MASKA>
__device__ __forceinline__ void streamW(const float* __restrict__ src0,
                                        const float* __restrict__ src1, int splitc,
                                        const short* __restrict__ wsB,
                                        const float* __restrict__ bias,
                                        short* X, short* Aout, float* maskacc,
                                        int row0, int lane) {
  constexpr int KT16 = NCH * 8;
  const int n32 = lane & 31, q32 = lane >> 5;
  f32x16 acc[4];
#pragma unroll
  for (int ct = 0; ct < 4; ++ct) acc[ct] = (f32x16)(0.f);
#pragma unroll
  for (int kc = 0; kc < NCH; ++kc) {
    const bool lo = (kc < splitc);
    const float* src = lo ? src0 : src1;
    const int colbase = (lo ? kc : kc - splitc) * 128;
    const int mm = MASKA ? (kc == 0 ? 1 : (lo ? 2 : 0)) : 0;
    stage_chunk<MASKA>(src, row0, colbase, X, maskacc, mm, lane);
    gemmW<KT16, 8, 4>(X, 136, wsB, kc * 8, 0, acc, lane);
  }
  epiW<4, 1>(acc, Aout, 136, bias, 0, n32, q32);
}

// Layer pair: (K=128 -> N=256, ReLU) then (K=256 -> N=128, ReLU), the 256-wide
// intermediate processed in four 64-col quarters through Z (acc-chain). A->A.
__device__ __forceinline__ void mid_pair(short* A, short* Z,
                                         const short* __restrict__ ws1,
                                         const float* __restrict__ b1,
                                         const short* __restrict__ ws2,
                                         const float* __restrict__ b2,
                                         int lane) {
  const int n32 = lane & 31, q32 = lane >> 5;
  f32x16 acc2[4];
#pragma unroll
  for (int ct = 0; ct < 4; ++ct) acc2[ct] = (f32x16)(0.f);
#pragma unroll
  for (int q = 0; q < 4; ++q) {
    f32x16 acc1[2];
    acc1[0] = (f32x16)(0.f); acc1[1] = (f32x16)(0.f);
    gemmW<8, 8, 2>(A, 136, ws1, 0, q * 2, acc1, lane);      // L1 cols q*64..q*64+63
    epiW<2, 1>(acc1, Z, 72, b1 + q * 64, 0, n32, q32);      // local cols 0..63
    gemmW<16, 4, 4>(Z, 72, ws2, q * 4, 0, acc2, lane);      // L2 k-slice q*64..
  }
  epiW<4, 1>(acc2, A, 136, b2, 0, n32, q32);                // overwrite A (reads done)
}

// Fused last layers: per column-quarter, gate-L3 (sigmoid) and val-L3 computed
// together, then mask*gate*val reduced over this wave's 32 rows + atomicAdd.
__device__ __forceinline__ void final_fuse(const short* Ag, const short* Av,
                                           const short* __restrict__ wsg,
                                           const float* __restrict__ bg,
                                           const short* __restrict__ wsv,
                                           const float* __restrict__ bv,
                                           const float* maskacc, float* __restrict__ out,
                                           int bidx, int lane) {
  const int n32 = lane & 31, q32 = lane >> 5;
#pragma unroll
  for (int q = 0; q < 4; ++q) {
    f32x16 ag[2]; ag[0] = (f32x16)(0.f); ag[1] = (f32x16)(0.f);
    gemmW<8, 8, 2>(Ag, 136, wsg, 0, q * 2, ag, lane);
    f32x16 av[2]; av[0] = (f32x16)(0.f); av[1] = (f32x16)(0.f);
    gemmW<8, 8, 2>(Av, 136, wsv, 0, q * 2, av, lane);
#pragma unroll
    for (int ct = 0; ct < 2; ++ct) {
      const int c = q * 64 + ct * 32 + n32;
      const float gb = bg[c], ob = bv[c];
      float s = 0.f;
#pragma unroll
      for (int reg = 0; reg < 16; ++reg) {
        const int r = (reg & 3) + 8 * (reg >> 2) + 4 * q32;
        if (maskacc[r] > 0.f) {
          const float g = 1.f / (1.f + __expf(-(ag[ct][reg] + gb)));
          s += g * (av[ct][reg] + ob);
        }
      }
      s += __shfl_down(s, 32);
      if (lane < 32) atomicAdd(out + bidx * 256 + c, s);
    }
  }
}

__global__ __launch_bounds__(NTHR, 2)
void readout_main(const float* __restrict__ h0, const float* __restrict__ hT,
                  const short* __restrict__ ws,
                  const float* __restrict__ gb0, const float* __restrict__ gb1,
                  const float* __restrict__ gb2, const float* __restrict__ gb3,
                  const float* __restrict__ ob0, const float* __restrict__ ob1,
                  const float* __restrict__ ob2, const float* __restrict__ ob3,
                  float* __restrict__ out) {
  __shared__ __align__(16) char smem[LDS_TOTAL];
  short* X = (short*)(smem + OFF_X);       // staging, then A_v
  short* Y = (short*)(smem + OFF_Y);       // A_g
  short* Z = (short*)(smem + OFF_Z);       // mid quarter buffer
  float* maskacc = (float*)(smem + OFF_M);

  const int lane = threadIdx.x;            // 64-thread WG = 1 wave
  const int row0 = blockIdx.x * ROWS;
  const int bidx = row0 >> 8;              // 32 | 256 -> 8 WGs per batch

  // gate chain: [h0; hT] (K=512) -> 128 -> 256 -> 128, output in Y
  streamW<4, true>(h0, hT, 2, ws + 0, gb0, X, Y, maskacc, row0, lane);
  mid_pair(Y, Z, ws + 65536, gb1, ws + 98304, gb2, lane);
  // value chain: hT (K=256) -> 128 -> 256 -> 128, output in X
  streamW<2, false>(hT, hT, 2, ws + 163840, ob0, X, X, maskacc, row0, lane);
  mid_pair(X, Z, ws + 196608, ob1, ws + 229376, ob2, lane);
  // fused gate-L3 (sigmoid) + val-L3 + mask*gate*val reduce
  final_fuse(Y, X, ws + 131072, gb3, ws + 262144, ob3, maskacc, out, bidx, lane);
}

// ---- prep: weights fp32[K][N] -> bf16 fragment-ordered; zero out -----------
// ws elem off = layer_off + ((cb*(K/16) + ks)<<9) + lanei*8 + j
//   with n = cb*32 + (lanei&31), k = ks*16 + (lanei>>5)*8 + j.
__global__ void prep(const float* __restrict__ W0, const float* __restrict__ W1,
                     const float* __restrict__ W2, const float* __restrict__ W3,
                     const float* __restrict__ W4, const float* __restrict__ W5,
                     const float* __restrict__ W6, const float* __restrict__ W7,
                     short* __restrict__ ws, float* __restrict__ out) {
  const int l = blockIdx.y;
  const int le = blockIdx.x * 256 + threadIdx.x;    // < 65536
  if (l == 1) { out[le] = 0.f; out[le + 65536] = 0.f; }
  int K, N, off; const float* W;
  switch (l) {
    case 0:  K = 512; N = 128; off = 0;      W = W0; break;
    case 1:  K = 128; N = 256; off = 65536;  W = W1; break;
    case 2:  K = 256; N = 128; off = 98304;  W = W2; break;
    case 3:  K = 128; N = 256; off = 131072; W = W3; break;
    case 4:  K = 256; N = 128; off = 163840; W = W4; break;
    case 5:  K = 128; N = 256; off = 196608; W = W5; break;
    case 6:  K = 256; N = 128; off = 229376; W = W6; break;
    default: K = 128; N = 256; off = 262144; W = W7; break;
  }
  if (le >= K * N) return;
  const int j = le & 7;
  const int lanei = (le >> 3) & 63;
  const int blk = le >> 9;
  const int kt16 = K >> 4;
  const int ks = blk % kt16, cb = blk / kt16;
  const int n = cb * 32 + (lanei & 31);
  const int k = ks * 16 + (lanei >> 5) * 8 + j;
  ws[off + le] = f2bf(W[k * N + n]);    // coalesced write, gathered read
}

extern "C" void kernel_launch(void* const* d_in, const int* in_sizes, int n_in,
                              void* d_out, int out_size, void* d_ws, size_t ws_size,
                              hipStream_t stream) {
  const float* h0  = (const float*)d_in[0];
  const float* hT  = (const float*)d_in[1];
  const float* gW0 = (const float*)d_in[2];  const float* gb0 = (const float*)d_in[3];
  const float* gW1 = (const float*)d_in[4];  const float* gb1 = (const float*)d_in[5];
  const float* gW2 = (const float*)d_in[6];  const float* gb2 = (const float*)d_in[7];
  const float* gW3 = (const float*)d_in[8];  const float* gb3 = (const float*)d_in[9];
  const float* oW0 = (const float*)d_in[10]; const float* ob0 = (const float*)d_in[11];
  const float* oW1 = (const float*)d_in[12]; const float* ob1 = (const float*)d_in[13];
  const float* oW2 = (const float*)d_in[14]; const float* ob2 = (const float*)d_in[15];
  const float* oW3 = (const float*)d_in[16]; const float* ob3 = (const float*)d_in[17];
  float* out = (float*)d_out;
  short* ws  = (short*)d_ws;   // 589824 B

  prep<<<dim3(256, 8), 256, 0, stream>>>(gW0, gW1, gW2, gW3, oW0, oW1, oW2, oW3, ws, out);
  readout_main<<<NWG, NTHR, 0, stream>>>(h0, hT, ws,
                                         gb0, gb1, gb2, gb3,
                                         ob0, ob1, ob2, ob3, out);
}

// Round 6
// 465.277 us; speedup vs baseline: 1.1260x; 1.1260x over previous
//
#include <hip/hip_runtime.h>
#include <hip/hip_bf16.h>
#include <stdint.h>

// ---------------------------------------------------------------------------
// Round 9: wave-chain (r8 structure) at 12 waves/CU. 1 wave = 1 WG = 32 rows,
// whole 8-layer chain private, zero __syncthreads.
//  - Y (A_g buffer) eliminated: after the gate chain, A_g is loaded once as
//    8 ds_read_b128 = 32 VGPRs of pre-formed MFMA A-fragments (gemmRA) and
//    stays in regs across the value chain.
//  - LDS/WG: X [32][132] (staging / A_v, stride 264 B -> 2-way bank alias,
//    free) + Z [32][72] scratch + mask = 13184 B -> 12 WGs/CU (vs r8's 7).
//  - __launch_bounds__(64,3): cap 170; staging split into 2x8 float4 groups
//    so peak live ~145 -> no spill (r7b: cap-128 spilled 250 MB).
// Same fragment-ordered ws layout + prep kernel as r4-r8 (verified).
// ---------------------------------------------------------------------------

typedef __attribute__((ext_vector_type(8))) short short8_t;
typedef __attribute__((ext_vector_type(16))) float f32x16;

#define ROWS 32
#define NWG  4096            // 131072 / 32
#define NTHR 64

#define SA 132               // X row stride (shorts): 264 B -> 2-way alias, free
#define SZ 72                // Z row stride (shorts)

// LDS layout (bytes)
#define OFF_X 0              // [32][132] shorts = 8448 (staging, A_g temp, A_v)
#define OFF_Z 8448           // [32][72]  shorts = 4608 (mid-layer quarter buf)
#define OFF_M 13056          // 32 floats = 128
#define LDS_TOTAL 13184

__device__ __forceinline__ short f2bf(float f) {
  union { float f; uint32_t u; } v; v.f = f;
  uint32_t r = (v.u + 0x7FFFu + ((v.u >> 16) & 1u)) >> 16;  // RNE
  return (short)r;
}

// ---- MFMA block: A from LDS (row = lane&31), B coalesced from fragment-
// ordered global. Weight elem off = ((cb*KT16 + ks)<<9) + lane*8 + j
//   -> logical n = cb*32 + (lane&31), k = ks*16 + (lane>>5)*8 + j.
// A: lane n32 -> act row n32, k = ks*16 + q32*8 + j (local; ks0 offsets only
// B, so partial-K passes read A with local k). Dual k-mapping matches B's,
// so any k-permutation cancels in the dot product.
template <int KT16, int KSTEPS, int CT>
__device__ __forceinline__ void gemmW(const short* actin, int Sin,
                                      const short* __restrict__ wsB, int ks0, int cb0,
                                      f32x16 (&acc)[CT], int lane) {
  const int n32 = lane & 31, q32 = lane >> 5;
#pragma unroll
  for (int ks = 0; ks < KSTEPS; ++ks) {
    const int kl = ks * 16 + q32 * 8;
    short8_t b[CT];
#pragma unroll
    for (int ct = 0; ct < CT; ++ct)
      b[ct] = *(const short8_t*)(wsB + (((cb0 + ct) * KT16 + ks0 + ks) << 9) + lane * 8);
    const short8_t a = *(const short8_t*)(actin + n32 * Sin + kl);
#pragma unroll
    for (int ct = 0; ct < CT; ++ct)
      acc[ct] = __builtin_amdgcn_mfma_f32_32x32x16_bf16(a, b[ct], acc[ct], 0, 0, 0);
  }
}

// Same, but A-fragments come from registers (aR[ks]), K=128 fixed (8 steps).
template <int KT16, int CT>
__device__ __forceinline__ void gemmRA(const short8_t (&aR)[8],
                                       const short* __restrict__ wsB, int cb0,
                                       f32x16 (&acc)[CT], int lane) {
#pragma unroll
  for (int ks = 0; ks < 8; ++ks) {
    short8_t b[CT];
#pragma unroll
    for (int ct = 0; ct < CT; ++ct)
      b[ct] = *(const short8_t*)(wsB + (((cb0 + ct) * KT16 + ks) << 9) + lane * 8);
#pragma unroll
    for (int ct = 0; ct < CT; ++ct)
      acc[ct] = __builtin_amdgcn_mfma_f32_32x32x16_bf16(aR[ks], b[ct], acc[ct], 0, 0, 0);
  }
}

// C/D layout (verified m74/m101): col = lane&31, row = (reg&3)+8*(reg>>2)+4*(lane>>5)
template <int CT, int ACTF>
__device__ __forceinline__ void epiW(f32x16 (&acc)[CT], short* actout, int Sout,
                                     const float* __restrict__ bias, int c0,
                                     int n32, int q32) {
#pragma unroll
  for (int ct = 0; ct < CT; ++ct) {
    const int c = c0 + ct * 32 + n32;
    const float bv = bias[c];
#pragma unroll
    for (int reg = 0; reg < 16; ++reg) {
      const int r = (reg & 3) + 8 * (reg >> 2) + 4 * q32;
      float v = acc[ct][reg] + bv;
      if (ACTF == 1) v = fmaxf(v, 0.f);
      actout[r * Sout + c] = f2bf(v);
    }
  }
}

// ---- input staging: one chunk = 32 rows x 128 cols fp32 -> bf16 LDS -------
// Split into two 16-row groups to cap live staging regs at ~32.
// mmode: 0 none, 1 init maskacc, 2 accumulate (mask = row-sum of h0).
template <bool MASKA>
__device__ __forceinline__ void stage_chunk(const float* __restrict__ src, int row0,
                                            int colbase, short* X, float* maskacc,
                                            int mmode, int lane) {
  const int c4 = lane & 31, rh = lane >> 5;
#pragma unroll
  for (int g = 0; g < 2; ++g) {
    float4 v[8];
#pragma unroll
    for (int it = 0; it < 8; ++it)
      v[it] = *(const float4*)(src + (size_t)(row0 + g * 16 + 2 * it + rh) * 256 + colbase + c4 * 4);
#pragma unroll
    for (int it = 0; it < 8; ++it) {
      const int r = g * 16 + 2 * it + rh;
      short4 pk; pk.x = f2bf(v[it].x); pk.y = f2bf(v[it].y); pk.z = f2bf(v[it].z); pk.w = f2bf(v[it].w);
      *(short4*)(X + r * SA + c4 * 4) = pk;
      if (MASKA && mmode) {
        float s = v[it].x + v[it].y + v[it].z + v[it].w;
        s += __shfl_down(s, 16, 32);
        s += __shfl_down(s, 8, 32);
        s += __shfl_down(s, 4, 32);
        s += __shfl_down(s, 2, 32);
        s += __shfl_down(s, 1, 32);
        if (c4 == 0) {
          if (mmode == 1) maskacc[r] = s; else maskacc[r] += s;
        }
      }
    }
  }
}

// Streamed first layer (K = NCH*128, N=128 out, CT=4). Chunks kc<splitc from
// src0, else src1. Staging and output both in X (in-place; single-wave
// program order makes read-before-overwrite safe).
template <int NCH, bool MASKA>
__device__ __forceinline__ void streamW(const float* __restrict__ src0,
                                        const float* __restrict__ src1, int splitc,
                                        const short* __restrict__ wsB,
                                        const float* __restrict__ bias,
                                        short* X, float* maskacc,
                                        int row0, int lane) {
  constexpr int KT16 = NCH * 8;
  const int n32 = lane & 31, q32 = lane >> 5;
  f32x16 acc[4];
#pragma unroll
  for (int ct = 0; ct < 4; ++ct) acc[ct] = (f32x16)(0.f);
#pragma unroll
  for (int kc = 0; kc < NCH; ++kc) {
    const bool lo = (kc < splitc);
    const float* src = lo ? src0 : src1;
    const int colbase = (lo ? kc : kc - splitc) * 128;
    const int mm = MASKA ? (kc == 0 ? 1 : (lo ? 2 : 0)) : 0;
    stage_chunk<MASKA>(src, row0, colbase, X, maskacc, mm, lane);
    gemmW<KT16, 8, 4>(X, SA, wsB, kc * 8, 0, acc, lane);
  }
  epiW<4, 1>(acc, X, SA, bias, 0, n32, q32);
}

// Layer pair: (K=128 -> N=256, ReLU) then (K=256 -> N=128, ReLU), the 256-wide
// intermediate processed in four 64-col quarters through Z (acc-chain). A->A.
__device__ __forceinline__ void mid_pair(short* A, short* Z,
                                         const short* __restrict__ ws1,
                                         const float* __restrict__ b1,
                                         const short* __restrict__ ws2,
                                         const float* __restrict__ b2,
                                         int lane) {
  const int n32 = lane & 31, q32 = lane >> 5;
  f32x16 acc2[4];
#pragma unroll
  for (int ct = 0; ct < 4; ++ct) acc2[ct] = (f32x16)(0.f);
#pragma unroll
  for (int q = 0; q < 4; ++q) {
    f32x16 acc1[2];
    acc1[0] = (f32x16)(0.f); acc1[1] = (f32x16)(0.f);
    gemmW<8, 8, 2>(A, SA, ws1, 0, q * 2, acc1, lane);       // L1 cols q*64..q*64+63
    epiW<2, 1>(acc1, Z, SZ, b1 + q * 64, 0, n32, q32);      // local cols 0..63
    gemmW<16, 4, 4>(Z, SZ, ws2, q * 4, 0, acc2, lane);      // L2 k-slice q*64..
  }
  epiW<4, 1>(acc2, A, SA, b2, 0, n32, q32);                 // overwrite A (reads done)
}

// Fused last layers: per column-quarter, gate-L3 (sigmoid, A from regs) and
// val-L3 (A from LDS) together, then mask*gate*val reduced + atomicAdd.
__device__ __forceinline__ void final_fuse(const short8_t (&aG)[8], const short* Av,
                                           const short* __restrict__ wsg,
                                           const float* __restrict__ bg,
                                           const short* __restrict__ wsv,
                                           const float* __restrict__ bv,
                                           const float* maskacc, float* __restrict__ out,
                                           int bidx, int lane) {
  const int n32 = lane & 31, q32 = lane >> 5;
#pragma unroll
  for (int q = 0; q < 4; ++q) {
    f32x16 ag[2]; ag[0] = (f32x16)(0.f); ag[1] = (f32x16)(0.f);
    gemmRA<8, 2>(aG, wsg, q * 2, ag, lane);
    f32x16 av[2]; av[0] = (f32x16)(0.f); av[1] = (f32x16)(0.f);
    gemmW<8, 8, 2>(Av, SA, wsv, 0, q * 2, av, lane);
#pragma unroll
    for (int ct = 0; ct < 2; ++ct) {
      const int c = q * 64 + ct * 32 + n32;
      const float gb = bg[c], ob = bv[c];
      float s = 0.f;
#pragma unroll
      for (int reg = 0; reg < 16; ++reg) {
        const int r = (reg & 3) + 8 * (reg >> 2) + 4 * q32;
        if (maskacc[r] > 0.f) {
          const float g = 1.f / (1.f + __expf(-(ag[ct][reg] + gb)));
          s += g * (av[ct][reg] + ob);
        }
      }
      s += __shfl_down(s, 32);
      if (lane < 32) atomicAdd(out + bidx * 256 + c, s);
    }
  }
}

__global__ __launch_bounds__(NTHR, 3)
void readout_main(const float* __restrict__ h0, const float* __restrict__ hT,
                  const short* __restrict__ ws,
                  const float* __restrict__ gb0, const float* __restrict__ gb1,
                  const float* __restrict__ gb2, const float* __restrict__ gb3,
                  const float* __restrict__ ob0, const float* __restrict__ ob1,
                  const float* __restrict__ ob2, const float* __restrict__ ob3,
                  float* __restrict__ out) {
  __shared__ __align__(16) char smem[LDS_TOTAL];
  short* X = (short*)(smem + OFF_X);       // staging / A_g temp / A_v
  short* Z = (short*)(smem + OFF_Z);       // mid quarter buffer
  float* maskacc = (float*)(smem + OFF_M);

  const int lane = threadIdx.x;            // 64-thread WG = 1 wave
  const int row0 = blockIdx.x * ROWS;
  const int bidx = row0 >> 8;              // 32 | 256 -> 8 WGs per batch
  const int n32 = lane & 31, q32 = lane >> 5;

  // gate chain: [h0; hT] (K=512) -> 128 -> 256 -> 128, result in X
  streamW<4, true>(h0, hT, 2, ws + 0, gb0, X, maskacc, row0, lane);
  mid_pair(X, Z, ws + 65536, gb1, ws + 98304, gb2, lane);
  // park A_g in regs as pre-formed MFMA A-fragments (8 x ds_read_b128)
  short8_t aG[8];
#pragma unroll
  for (int ks = 0; ks < 8; ++ks)
    aG[ks] = *(const short8_t*)(X + n32 * SA + ks * 16 + q32 * 8);
  // value chain: hT (K=256) -> 128 -> 256 -> 128, result in X (overwrites)
  streamW<2, false>(hT, hT, 2, ws + 163840, ob0, X, maskacc, row0, lane);
  mid_pair(X, Z, ws + 196608, ob1, ws + 229376, ob2, lane);
  // fused gate-L3 (sigmoid, regs) + val-L3 (LDS) + mask*gate*val reduce
  final_fuse(aG, X, ws + 131072, gb3, ws + 262144, ob3, maskacc, out, bidx, lane);
}

// ---- prep: weights fp32[K][N] -> bf16 fragment-ordered; zero out -----------
// ws elem off = layer_off + ((cb*(K/16) + ks)<<9) + lanei*8 + j
//   with n = cb*32 + (lanei&31), k = ks*16 + (lanei>>5)*8 + j.
__global__ void prep(const float* __restrict__ W0, const float* __restrict__ W1,
                     const float* __restrict__ W2, const float* __restrict__ W3,
                     const float* __restrict__ W4, const float* __restrict__ W5,
                     const float* __restrict__ W6, const float* __restrict__ W7,
                     short* __restrict__ ws, float* __restrict__ out) {
  const int l = blockIdx.y;
  const int le = blockIdx.x * 256 + threadIdx.x;    // < 65536
  if (l == 1) { out[le] = 0.f; out[le + 65536] = 0.f; }
  int K, N, off; const float* W;
  switch (l) {
    case 0:  K = 512; N = 128; off = 0;      W = W0; break;
    case 1:  K = 128; N = 256; off = 65536;  W = W1; break;
    case 2:  K = 256; N = 128; off = 98304;  W = W2; break;
    case 3:  K = 128; N = 256; off = 131072; W = W3; break;
    case 4:  K = 256; N = 128; off = 163840; W = W4; break;
    case 5:  K = 128; N = 256; off = 196608; W = W5; break;
    case 6:  K = 256; N = 128; off = 229376; W = W6; break;
    default: K = 128; N = 256; off = 262144; W = W7; break;
  }
  if (le >= K * N) return;
  const int j = le & 7;
  const int lanei = (le >> 3) & 63;
  const int blk = le >> 9;
  const int kt16 = K >> 4;
  const int ks = blk % kt16, cb = blk / kt16;
  const int n = cb * 32 + (lanei & 31);
  const int k = ks * 16 + (lanei >> 5) * 8 + j;
  ws[off + le] = f2bf(W[k * N + n]);    // coalesced write, gathered read
}

extern "C" void kernel_launch(void* const* d_in, const int* in_sizes, int n_in,
                              void* d_out, int out_size, void* d_ws, size_t ws_size,
                              hipStream_t stream) {
  const float* h0  = (const float*)d_in[0];
  const float* hT  = (const float*)d_in[1];
  const float* gW0 = (const float*)d_in[2];  const float* gb0 = (const float*)d_in[3];
  const float* gW1 = (const float*)d_in[4];  const float* gb1 = (const float*)d_in[5];
  const float* gW2 = (const float*)d_in[6];  const float* gb2 = (const float*)d_in[7];
  const float* gW3 = (const float*)d_in[8];  const float* gb3 = (const float*)d_in[9];
  const float* oW0 = (const float*)d_in[10]; const float* ob0 = (const float*)d_in[11];
  const float* oW1 = (const float*)d_in[12]; const float* ob1 = (const float*)d_in[13];
  const float* oW2 = (const float*)d_in[14]; const float* ob2 = (const float*)d_in[15];
  const float* oW3 = (const float*)d_in[16]; const float* ob3 = (const float*)d_in[17];
  float* out = (float*)d_out;
  short* ws  = (short*)d_ws;   // 589824 B

  prep<<<dim3(256, 8), 256, 0, stream>>>(gW0, gW1, gW2, gW3, oW0, oW1, oW2, oW3, ws, out);
  readout_main<<<NWG, NTHR, 0, stream>>>(h0, hT, ws,
                                         gb0, gb1, gb2, gb3,
                                         ob0, ob1, ob2, ob3, out);
}